// Round 3
// baseline (106.336 us; speedup 1.0000x reference)
//
#include <hip/hip_runtime.h>

#define BATCH   8
#define NCLS    6
#define HW      512
#define IMGPIX  (HW * HW)                 // 262144 = 2^18
#define NPIX    (BATCH * IMGPIX)          // 2097152 = 2^21
#define TILE    32
#define HALO    5
#define SM      (TILE + 2 * HALO)         // 42
#define RSTRIDE 36                        // padded stride for h-sum array
#define NB      (BATCH * 128)             // 1024 blocks = exact residency (4/CU)

__device__ __forceinline__ float get4(const float4& v, int j) {
    return j == 0 ? v.x : j == 1 ? v.y : j == 2 ? v.z : v.w;
}

// LDS-only barrier: drains this wave's ds ops (lgkmcnt) + rendezvous, but
// does NOT drain vmcnt — outstanding global loads stay in flight across it.
// sched_barrier(0) on both edges stops the scheduler from moving LDS ops
// across the hand-rolled sync (guide rule #18). Race-free: each wave's own
// lgkmcnt(0) retires its ds_writes/reads before the rendezvous, so all
// pre-barrier LDS traffic is complete before any wave proceeds.
__device__ __forceinline__ void lds_only_barrier() {
    __builtin_amdgcn_sched_barrier(0);
    asm volatile("s_waitcnt lgkmcnt(0)" ::: "memory");
    __builtin_amdgcn_s_barrier();
    __builtin_amdgcn_sched_barrier(0);
}

// ---------------------------------------------------------------------------
// R11 = the discriminating experiment: true 2-stage pipeline.
//   R9  (2 tiles, __syncthreads)      = FAILED (+5.4): its barriers drained
//        vmcnt(0), serializing ALL 26 loads before any compute.
//   R10 (1 tile, lds-only barriers)   = NEUTRAL: structurally a no-op — all
//        13 loads issue together and land together; nothing useful was left
//        in flight for the barriers to preserve.
//   R11 = R9 geometry + R10 barriers: tile-1's 31.7 KB stays outstanding
//        through tile-0's whole LDS/compute pipeline. Counted waits (issue
//        order tva, xc, tvb, xd): t0 ds_write vmcnt(19)->t0 arrival;
//        t1 ds_write vmcnt(6); t1 softmax vmcnt(0). Never a full drain
//        until the last consumer.
// Pre-commit: big win => duty-cycle theory (D1) confirmed, keep tuning;
// neutral => main is already at its ~11us HBM floor (D2), declare roofline.
//
// HARD-WON LESSONS preserved:
//   - NO single-kernel finalize protocol (atomics = 6x slower main body).
//   - tgt goes global->reg->LDS with uniform coalesced loads.
//   - launch_bounds(256,4): 128-VGPR cap. Live data regs here ~62 + temps.
//   - No max-sub in softmax: N(0,1) inputs, exp cannot overflow.
//   - Exact e/SM division (compiler magic-mul).
//   - No __syncthreads() anywhere in the main kernel (it drains vmcnt).
// ---------------------------------------------------------------------------
__global__ __launch_bounds__(256, 4) void ls_main_kernel(
        const float* __restrict__ x,
        const int*   __restrict__ tgt,
        float4*      __restrict__ part) { // per block: {R1, R2, E, 0}
    __shared__ int   s_t[SM * SM];        // halo'd target tile (flat)
    __shared__ int   s_rs[SM][RSTRIDE];   // horizontal 11-sums
    __shared__ float sw1[4], sw2[4];
    __shared__ int   swe[4];

    const int tid = threadIdx.x;
    const int blk = blockIdx.x;
    const int b   = blk & 7;              // XCD-aware: image index = XCD id
    const int tp  = blk >> 3;             // 128 tile-pairs per image (16 x 8)
    const int tr  = (tp >> 3) * TILE;
    const int tc0 = (tp & 7) * (2 * TILE);
    const int tc1 = tc0 + TILE;

    const int* timg = tgt + b * IMGPIX;

    // ---- issue ALL loads up-front, order pinned: tva, xc, tvb, xd -------
    int tva[7];
#pragma unroll
    for (int i = 0; i < 7; i++) {
        const int e  = tid + i * 256;
        const int ly = e / SM;            // exact division (compiler magic)
        const int lx = e - ly * SM;
        int v = 0;
        if (e < SM * SM) {
            const int gy = tr - HALO + ly, gx = tc0 - HALO + lx;
            if (gy >= 0 && gy < HW && gx >= 0 && gx < HW) v = timg[gy * HW + gx];
        }
        tva[i] = v;
    }

    const int py = tid >> 3;              // row within tile
    const int px = (tid & 7) << 2;        // quad col
    const float* xr = x + ((size_t)(b * NCLS) << 18) + ((size_t)(tr + py) << 9);
    float4 xc[NCLS];
#pragma unroll
    for (int c = 0; c < NCLS; c++)
        xc[c] = *(const float4*)(xr + ((size_t)c << 18) + (tc0 + px));

    int tvb[7];
#pragma unroll
    for (int i = 0; i < 7; i++) {
        const int e  = tid + i * 256;
        const int ly = e / SM;
        const int lx = e - ly * SM;
        int v = 0;
        if (e < SM * SM) {
            const int gy = tr - HALO + ly, gx = tc1 - HALO + lx;
            if (gy >= 0 && gy < HW && gx >= 0 && gx < HW) v = timg[gy * HW + gx];
        }
        tvb[i] = v;
    }

    float4 xd[NCLS];
#pragma unroll
    for (int c = 0; c < NCLS; c++)
        xd[c] = *(const float4*)(xr + ((size_t)c << 18) + (tc1 + px));
    __builtin_amdgcn_sched_barrier(0);    // pin issue order above this point

    float r1 = 0.f, r2 = 0.f;
    int   ec = 0;

    // ========================== tile 0 ===================================
#pragma unroll
    for (int i = 0; i < 7; i++) {         // ds_write waits vmcnt(19): t0 tgt
        const int e = tid + i * 256;
        if (e < SM * SM) s_t[e] = tva[i];
    }
    lds_only_barrier();                   // 19 loads remain in flight

    if (tid < SM * 4) {                   // horizontal 11-sums
        const int row  = tid >> 2;
        const int c0   = (tid & 3) << 3;
        const int base = row * SM + c0;
        int buf[18];
#pragma unroll
        for (int k = 0; k < 18; k++) buf[k] = s_t[base + k];
        int acc = 0;
#pragma unroll
        for (int k = 0; k < 11; k++) acc += buf[k];
        s_rs[row][c0] = acc;
#pragma unroll
        for (int k = 1; k < 8; k++) {
            acc += buf[k + 10] - buf[k - 1];
            s_rs[row][c0 + k] = acc;
        }
    }
    lds_only_barrier();

    int4 bs0 = make_int4(0, 0, 0, 0);     // vertical 11-sum + center targets
#pragma unroll
    for (int dy = 0; dy <= 2 * HALO; dy++) {
        const int4 r = *(const int4*)&s_rs[py + dy][px];
        bs0.x += r.x; bs0.y += r.y; bs0.z += r.z; bs0.w += r.w;
    }
    const int bsa[4] = {bs0.x, bs0.y, bs0.z, bs0.w};
    int t4a[4];
#pragma unroll
    for (int j = 0; j < 4; j++) t4a[j] = s_t[(py + HALO) * SM + px + HALO + j];
    lds_only_barrier();                   // t0 LDS fully consumed

    // t1 ds_write (waits vmcnt(6): only xd still outstanding) ...
#pragma unroll
    for (int i = 0; i < 7; i++) {
        const int e = tid + i * 256;
        if (e < SM * SM) s_t[e] = tvb[i];
    }
    // ... overlapped with t0 softmax (xc is older than tvb: already landed)
#pragma unroll
    for (int j = 0; j < 4; j++) {
        const float a0 = get4(xc[0], j), a1 = get4(xc[1], j), a2 = get4(xc[2], j);
        const float a3 = get4(xc[3], j), a4 = get4(xc[4], j), a5 = get4(xc[5], j);
        const float se = __expf(a0) + __expf(a1) + __expf(a2) +
                         __expf(a3) + __expf(a4) + __expf(a5);
        const float lse = __logf(se);
        const int   t   = t4a[j];
        const float xt  = t == 0 ? a0 : t == 1 ? a1 : t == 2 ? a2 :
                          t == 3 ? a3 : t == 4 ? a4 : a5;
        const float lpl = xt - lse;
        r1 += lpl;
        const int ev = 121 * t - bsa[j];  // exact integer edge test
        const int eb = (ev != 0) ? 1 : 0;
        const float S = (a0 + a1 + a2 + a3 + a4 + a5) - 6.f * lse;
        r2 = fmaf((float)eb, S - (11.0f / 6.0f) * lpl, r2);
        ec += eb;
    }
    lds_only_barrier();                   // t1 s_t visible

    // ========================== tile 1 ===================================
    if (tid < SM * 4) {
        const int row  = tid >> 2;
        const int c0   = (tid & 3) << 3;
        const int base = row * SM + c0;
        int buf[18];
#pragma unroll
        for (int k = 0; k < 18; k++) buf[k] = s_t[base + k];
        int acc = 0;
#pragma unroll
        for (int k = 0; k < 11; k++) acc += buf[k];
        s_rs[row][c0] = acc;
#pragma unroll
        for (int k = 1; k < 8; k++) {
            acc += buf[k + 10] - buf[k - 1];
            s_rs[row][c0 + k] = acc;
        }
    }
    lds_only_barrier();

    int4 bs1 = make_int4(0, 0, 0, 0);
#pragma unroll
    for (int dy = 0; dy <= 2 * HALO; dy++) {
        const int4 r = *(const int4*)&s_rs[py + dy][px];
        bs1.x += r.x; bs1.y += r.y; bs1.z += r.z; bs1.w += r.w;
    }
    const int bsb[4] = {bs1.x, bs1.y, bs1.z, bs1.w};
    int t4b[4];
#pragma unroll
    for (int j = 0; j < 4; j++) t4b[j] = s_t[(py + HALO) * SM + px + HALO + j];

#pragma unroll
    for (int j = 0; j < 4; j++) {         // first xd use -> vmcnt(0) here
        const float a0 = get4(xd[0], j), a1 = get4(xd[1], j), a2 = get4(xd[2], j);
        const float a3 = get4(xd[3], j), a4 = get4(xd[4], j), a5 = get4(xd[5], j);
        const float se = __expf(a0) + __expf(a1) + __expf(a2) +
                         __expf(a3) + __expf(a4) + __expf(a5);
        const float lse = __logf(se);
        const int   t   = t4b[j];
        const float xt  = t == 0 ? a0 : t == 1 ? a1 : t == 2 ? a2 :
                          t == 3 ? a3 : t == 4 ? a4 : a5;
        const float lpl = xt - lse;
        r1 += lpl;
        const int ev = 121 * t - bsb[j];
        const int eb = (ev != 0) ? 1 : 0;
        const float S = (a0 + a1 + a2 + a3 + a4 + a5) - 6.f * lse;
        r2 = fmaf((float)eb, S - (11.0f / 6.0f) * lpl, r2);
        ec += eb;
    }

    // ---- block reduction: wave shuffles + cross-wave LDS ----------------
#pragma unroll
    for (int off = 32; off > 0; off >>= 1) {
        r1 += __shfl_down(r1, off);
        r2 += __shfl_down(r2, off);
        ec += __shfl_down(ec, off);
    }
    const int wave = tid >> 6;
    if ((tid & 63) == 0) { sw1[wave] = r1; sw2[wave] = r2; swe[wave] = ec; }
    lds_only_barrier();
    if (tid == 0) {
        part[blk] = make_float4(sw1[0] + sw1[1] + sw1[2] + sw1[3],
                                sw2[0] + sw2[1] + sw2[2] + sw2[3],
                                (float)(swe[0] + swe[1] + swe[2] + swe[3]),
                                0.f);
    }
}

// ---------------------------------------------------------------------------
// Finalize: one block reduces NB float4 partials, applies scalar epilogue.
// Kernel boundary guarantees visibility of part[] — no atomics, no fences.
// ---------------------------------------------------------------------------
__global__ __launch_bounds__(256) void ls_finalize_kernel(
        const float4* __restrict__ part,
        float* __restrict__ out) {
    const int tid = threadIdx.x;
    double d1 = 0.0, d2 = 0.0, de = 0.0;
#pragma unroll
    for (int i = 0; i < NB / 256; i++) {
        const float4 p = part[tid + i * 256];
        d1 += (double)p.x;
        d2 += (double)p.y;
        de += (double)p.z;
    }
#pragma unroll
    for (int off = 32; off > 0; off >>= 1) {
        d1 += __shfl_down(d1, off);
        d2 += __shfl_down(d2, off);
        de += __shfl_down(de, off);
    }
    __shared__ double sd1[4], sd2[4], sde[4];
    const int wave = tid >> 6;
    if ((tid & 63) == 0) { sd1[wave] = d1; sd2[wave] = d2; sde[wave] = de; }
    __syncthreads();
    if (tid == 0) {
        const double R1 = sd1[0] + sd1[1] + sd1[2] + sd1[3];
        const double R2 = sd2[0] + sd2[1] + sd2[2] + sd2[3];
        const double E  = sde[0] + sde[1] + sde[2] + sde[3];
        // (float)E / 2^21 exact (E < 2^24) -> matches f32 reference's s
        const float  s  = fminf((float)E * (1.0f / (float)NPIX), 0.2f);
        const double loss = (R1 + (double)s * R2) * (1.0 / (double)NPIX);
        out[0] = (float)(-loss);
    }
}

extern "C" void kernel_launch(void* const* d_in, const int* in_sizes, int n_in,
                              void* d_out, int out_size, void* d_ws, size_t ws_size,
                              hipStream_t stream) {
    const float* x   = (const float*)d_in[0];
    const int*   tgt = (const int*)d_in[1];
    float*       out = (float*)d_out;
    float4*      part = (float4*)d_ws;    // NB float4s = 16 KB

    ls_main_kernel<<<NB, 256, 0, stream>>>(x, tgt, part);
    ls_finalize_kernel<<<1, 256, 0, stream>>>(part, out);
}

// Round 4
// 89.156 us; speedup vs baseline: 1.1927x; 1.1927x over previous
//
#include <hip/hip_runtime.h>

#define BATCH   8
#define NCLS    6
#define HW      512
#define IMGPIX  (HW * HW)                 // 262144 = 2^18
#define NPIX    (BATCH * IMGPIX)          // 2097152 = 2^21
#define TILE    32
#define HALO    5
#define SM      (TILE + 2 * HALO)         // 42
#define RSTRIDE 36                        // padded stride for h-sum array
#define NB      (BATCH * 256)             // 2048 blocks, one 32x32 tile each

__device__ __forceinline__ float get4(const float4& v, int j) {
    return j == 0 ? v.x : j == 1 ? v.y : j == 2 ? v.z : v.w;
}

// ---------------------------------------------------------------------------
// R12 = exact revert to R8 (best measured: 88.47 us). FINAL.
//
// SESSION CONCLUSION (R8->R11 evidence):
//   dur_us 88.5 decomposes as: harness workspace-poison fill 42.0 us
//   (268 MB @ 80% peak HBM, unconditional) + ~55-dispatch harness reset
//   train ~30 us (fill-to-fill Dispatch_Id spacing 54-66) + main ~13 us
//   (~1.3x its 10.3 us HBM floor: 65 MB @ 6.3 TB/s) + finalize ~2 us.
//   Controllable headroom is ~2-3 us; structural edits measured -5 to -18.
//
// EXPERIMENT LOG (do not retry):
//   R9  (2 tiles/block, __syncthreads): +5.4 us. __syncthreads drains
//       vmcnt(0) on gfx950, serializing all 26 up-front loads.
//   R10 (lgkmcnt-only barriers): +0.2 us (noise). Structurally a no-op:
//       all 13 loads issue together and land together; nothing useful
//       stays in flight for the barriers to preserve.
//   R11 (2 tiles + lgkm-only barriers): +17.7 us. 62 live data VGPRs ->
//       scratch spills (WRITE_SIZE 25.6 MB vs 16 KB stored, ~24 dwords
//       spilled/thread). 2-tile pipelining loses on either barrier flavor.
//
// HARD-WON LESSONS preserved (prior session):
//   - NO single-kernel finalize protocol. Agent-scope ACQ_REL atomics made
//     the main body 6x slower (L2 invalidation storm; 270 GB/s). Kernel-
//     boundary visibility via a separate finalize dispatch is cheaper.
//   - tgt goes global->reg->LDS with uniform coalesced loads. Direct
//     per-thread bounds-checked scalar loads poisoned the schedule.
//   - All global loads issued up-front: 7 coalesced tgt scalars, then 6
//     x-float4s.
//   - launch_bounds(256,4): 128-VGPR cap. (256,8) spilled 90 MB.
//   - No max-sub in softmax: N(0,1) inputs, exp cannot overflow
//     (error ~1e-6 vs 8e-2 threshold).
//   - Exact e/SM division (hand-rolled (e*1560)>>16 was wrong at e%42==0).
// ---------------------------------------------------------------------------
__global__ __launch_bounds__(256, 4) void ls_main_kernel(
        const float* __restrict__ x,
        const int*   __restrict__ tgt,
        float4*      __restrict__ part) { // per block: {R1, R2, E, 0}
    __shared__ int   s_t[SM * SM];        // halo'd target tile (flat)
    __shared__ int   s_rs[SM][RSTRIDE];   // horizontal 11-sums
    __shared__ float sw1[4], sw2[4];
    __shared__ int   swe[4];

    const int tid  = threadIdx.x;
    const int blk  = blockIdx.x;
    const int b    = blk & 7;             // XCD-aware: image index = XCD id
    const int tile = blk >> 3;            // 256 tiles (16x16) per image
    const int tr   = (tile >> 4) * TILE;
    const int tc   = (tile & 15) * TILE;

    const int* timg = tgt + b * IMGPIX;

    // ---- issue tgt halo loads (7 per thread, coalesced, independent) ----
    int tv[7];
#pragma unroll
    for (int i = 0; i < 7; i++) {
        const int e  = tid + i * 256;
        const int ly = e / SM;            // exact division (compiler magic)
        const int lx = e - ly * SM;
        int v = 0;
        if (e < SM * SM) {
            const int gy = tr - HALO + ly, gx = tc - HALO + lx;
            if (gy >= 0 && gy < HW && gx >= 0 && gx < HW) v = timg[gy * HW + gx];
        }
        tv[i] = v;
    }

    // ---- issue x loads (6 float4, independent; land during LDS phase) ----
    const int py = tid >> 3;              // row within tile
    const int px = (tid & 7) << 2;        // quad col
    const int gy = tr + py;
    const int gx = tc + px;
    const float* xb = x + ((size_t)(b * NCLS) << 18) + (gy << 9) + gx;
    float4 xc[NCLS];
#pragma unroll
    for (int c = 0; c < NCLS; c++)
        xc[c] = *(const float4*)(xb + ((size_t)c << 18));

    // ---- LDS: store tgt tile (flat, conflict-free) ----
#pragma unroll
    for (int i = 0; i < 7; i++) {
        const int e = tid + i * 256;
        if (e < SM * SM) s_t[e] = tv[i];
    }
    __syncthreads();

    // ---- horizontal 11-sums, sliding window: 8 outputs per thread ----
    // 42 rows x 4 segs of 8 cols = 168 threads; 18 reads + 8 writes each.
    if (tid < SM * 4) {
        const int row  = tid >> 2;
        const int c0   = (tid & 3) << 3;
        const int base = row * SM + c0;
        int buf[18];
#pragma unroll
        for (int k = 0; k < 18; k++) buf[k] = s_t[base + k];
        int acc = 0;
#pragma unroll
        for (int k = 0; k < 11; k++) acc += buf[k];
        s_rs[row][c0] = acc;
#pragma unroll
        for (int k = 1; k < 8; k++) {
            acc += buf[k + 10] - buf[k - 1];
            s_rs[row][c0 + k] = acc;
        }
    }
    __syncthreads();

    // ---- vertical 11-sum -> box sums for this thread's quad ----
    int4 bs = make_int4(0, 0, 0, 0);
#pragma unroll
    for (int dy = 0; dy <= 2 * HALO; dy++) {
        const int4 r = *(const int4*)&s_rs[py + dy][px];
        bs.x += r.x; bs.y += r.y; bs.z += r.z; bs.w += r.w;
    }
    const int bsa[4] = {bs.x, bs.y, bs.z, bs.w};
    int t4a[4];
#pragma unroll
    for (int j = 0; j < 4; j++) t4a[j] = s_t[(py + HALO) * SM + px + HALO + j];

    // ---- per-pixel log-softmax terms ----
    float r1 = 0.f, r2 = 0.f;
    int ec = 0;
#pragma unroll
    for (int j = 0; j < 4; j++) {
        const float a0 = get4(xc[0], j), a1 = get4(xc[1], j), a2 = get4(xc[2], j);
        const float a3 = get4(xc[3], j), a4 = get4(xc[4], j), a5 = get4(xc[5], j);
        const float se = __expf(a0) + __expf(a1) + __expf(a2) +
                         __expf(a3) + __expf(a4) + __expf(a5);
        const float lse = __logf(se);
        const int   t   = t4a[j];
        const float xt  = t == 0 ? a0 : t == 1 ? a1 : t == 2 ? a2 :
                          t == 3 ? a3 : t == 4 ? a4 : a5;
        const float lpl = xt - lse;
        r1 += lpl;
        const int ev = 121 * t - bsa[j];  // exact integer edge test
        const int eb = (ev != 0) ? 1 : 0;
        const float S = (a0 + a1 + a2 + a3 + a4 + a5) - 6.f * lse;
        r2 = fmaf((float)eb, S - (11.0f / 6.0f) * lpl, r2);
        ec += eb;
    }

    // ---- block reduction: wave shuffles + cross-wave LDS ----
#pragma unroll
    for (int off = 32; off > 0; off >>= 1) {
        r1 += __shfl_down(r1, off);
        r2 += __shfl_down(r2, off);
        ec += __shfl_down(ec, off);
    }
    const int wave = tid >> 6;
    if ((tid & 63) == 0) { sw1[wave] = r1; sw2[wave] = r2; swe[wave] = ec; }
    __syncthreads();
    if (tid == 0) {
        part[blk] = make_float4(sw1[0] + sw1[1] + sw1[2] + sw1[3],
                                sw2[0] + sw2[1] + sw2[2] + sw2[3],
                                (float)(swe[0] + swe[1] + swe[2] + swe[3]),
                                0.f);
    }
}

// ---------------------------------------------------------------------------
// Finalize: one block reduces NB float4 partials, applies scalar epilogue.
// Kernel boundary guarantees visibility of part[] — no atomics, no fences.
// ---------------------------------------------------------------------------
__global__ __launch_bounds__(256) void ls_finalize_kernel(
        const float4* __restrict__ part,
        float* __restrict__ out) {
    const int tid = threadIdx.x;
    double d1 = 0.0, d2 = 0.0, de = 0.0;
#pragma unroll
    for (int i = 0; i < NB / 256; i++) {
        const float4 p = part[tid + i * 256];
        d1 += (double)p.x;
        d2 += (double)p.y;
        de += (double)p.z;
    }
#pragma unroll
    for (int off = 32; off > 0; off >>= 1) {
        d1 += __shfl_down(d1, off);
        d2 += __shfl_down(d2, off);
        de += __shfl_down(de, off);
    }
    __shared__ double sd1[4], sd2[4], sde[4];
    const int wave = tid >> 6;
    if ((tid & 63) == 0) { sd1[wave] = d1; sd2[wave] = d2; sde[wave] = de; }
    __syncthreads();
    if (tid == 0) {
        const double R1 = sd1[0] + sd1[1] + sd1[2] + sd1[3];
        const double R2 = sd2[0] + sd2[1] + sd2[2] + sd2[3];
        const double E  = sde[0] + sde[1] + sde[2] + sde[3];
        // (float)E / 2^21 exact (E < 2^24) -> matches f32 reference's s
        const float  s  = fminf((float)E * (1.0f / (float)NPIX), 0.2f);
        const double loss = (R1 + (double)s * R2) * (1.0 / (double)NPIX);
        out[0] = (float)(-loss);
    }
}

extern "C" void kernel_launch(void* const* d_in, const int* in_sizes, int n_in,
                              void* d_out, int out_size, void* d_ws, size_t ws_size,
                              hipStream_t stream) {
    const float* x   = (const float*)d_in[0];
    const int*   tgt = (const int*)d_in[1];
    float*       out = (float*)d_out;
    float4*      part = (float4*)d_ws;    // NB float4s = 32 KB

    ls_main_kernel<<<NB, 256, 0, stream>>>(x, tgt, part);
    ls_finalize_kernel<<<1, 256, 0, stream>>>(part, out);
}